// Round 7
// baseline (365.731 us; speedup 1.0000x reference)
//
#include <hip/hip_runtime.h>
#include <hip/hip_bf16.h>
#include <algorithm>
#include <vector>
#include <cmath>

#define HH 96
#define WW 96
#define CC 21
#define NN (HH*WW)          // 9216
#define NELEM (NN*CC)       // 193536
#define RS 20
#define NPAR (2*CC + CC*CC)
#define L2E 1.4426950408889634f
#define NBLUR (CC*8)        // 168 blur items
#define SROWS 12
#define TRUNC2 1225         // 35^2
#define BLURKEY 0x10000
#define NSLOT 24            // max surviving m-chunks per n-tile

typedef short bf16x8 __attribute__((ext_vector_type(8)));
typedef float f32x16 __attribute__((ext_vector_type(16)));

__device__ __forceinline__ float fexp2(float x) { return __builtin_amdgcn_exp2f(x); }
__device__ __forceinline__ float fexp(float x)  { return __builtin_amdgcn_exp2f(x * L2E); }

__device__ __forceinline__ short f2b(float f) {
    __hip_bfloat16 h = __float2bfloat16(f);
    short s; __builtin_memcpy(&s, &h, 2); return s;
}

// ---- dtype sniff: bf16 data never contains exp=0xFF bit patterns.
__global__ void k_sniff(const unsigned short* __restrict__ u16, int* __restrict__ flag32) {
    __shared__ int sfound;
    if (threadIdx.x == 0) sfound = 0;
    __syncthreads();
    const int base = blockIdx.x * (NELEM/32);
    int found = 0;
    for (int i = base + threadIdx.x; i < base + NELEM/32; i += 256) {
        unsigned v = u16[i];
        if ((v & 0x7F80u) == 0x7F80u) found = 1;
    }
    if (found) sfound = 1;
    __syncthreads();
    if (threadIdx.x == 0) flag32[blockIdx.x] = sfound;
}

__device__ __forceinline__ int rdflag(const int* __restrict__ flag32) {
    int f = 0;
    #pragma unroll
    for (int i = 0; i < 32; i++) f |= flag32[i];
    return f;
}

// Fused prep: featx, params, softmax(u)->pT. (bil24 needs NO zeroing: every
// live slot-tile is fully overwritten by its block each iteration.)
__global__ __launch_bounds__(256) void k_prep(
    const void* __restrict__ u, const void* __restrict__ img,
    const void* __restrict__ wS, const void* __restrict__ wB,
    const void* __restrict__ compat, const int* __restrict__ flag32,
    float* __restrict__ uf, float* __restrict__ featx, float* __restrict__ par,
    __hip_bfloat16* __restrict__ pT)
{
    const int f = rdflag(flag32);
    const int tid = threadIdx.x;
    const int n = blockIdx.x * 256 + tid;

    if (blockIdx.x == 0) {
        for (int i = tid; i < NPAR; i += 256) {
            const void* src; int j;
            if (i < CC)        { src = wS;     j = i; }
            else if (i < 2*CC) { src = wB;     j = i - CC; }
            else               { src = compat; j = i - 2*CC; }
            par[i] = f ? ((const float*)src)[j]
                       : __bfloat162float(((const __hip_bfloat16*)src)[j]);
        }
    }
    {
        float c0, c1, c2;
        if (f) { const float* p = (const float*)img;
                 c0 = p[3*n]; c1 = p[3*n+1]; c2 = p[3*n+2]; }
        else   { const __hip_bfloat16* p = (const __hip_bfloat16*)img;
                 c0 = __bfloat162float(p[3*n]); c1 = __bfloat162float(p[3*n+1]);
                 c2 = __bfloat162float(p[3*n+2]); }
        float ym = (float)(n / WW), xm = (float)(n % WW);
        const float sc = 0.15014029f;   // sqrt(2*L2E/128)
        const float cf = 9.6089787f;    // sqrt(64*L2E)
        featx[8*n + 0] = -L2E * (fmaf(ym, ym, xm*xm) * 0.0078125f
                                 + 32.f * (c0*c0 + c1*c1 + c2*c2));
        featx[8*n + 1] = sc * ym;
        featx[8*n + 2] = sc * xm;
        featx[8*n + 3] = cf * c0;
        featx[8*n + 4] = cf * c1;
        featx[8*n + 5] = cf * c2;
        featx[8*n + 6] = 0.f;
        featx[8*n + 7] = 0.f;
    }

    float v[CC];
    float mx = -1e30f;
    #pragma unroll
    for (int c = 0; c < CC; c++) {
        float uv = f ? ((const float*)u)[n*CC + c]
                     : __bfloat162float(((const __hip_bfloat16*)u)[n*CC + c]);
        uf[n*CC + c] = uv;
        v[c] = uv;
        mx = fmaxf(mx, uv);
    }
    float s = 0.f;
    #pragma unroll
    for (int c = 0; c < CC; c++) { v[c] = fexp(v[c] - mx); s += v[c]; }
    float inv = 1.f / s;
    #pragma unroll
    for (int c = 0; c < CC; c++)
        pT[(size_t)c*NN + n] = __float2bfloat16(v[c] * inv);
}

// Work kernel: R3 structure (one block per (n-tile, m-chunk), LPT order), but
// results go to a PRIVATE slot with plain coalesced stores — zero atomics.
__global__ __launch_bounds__(256) void k_work(
    const __hip_bfloat16* __restrict__ pT,   // [32][NN] bf16 (rows 21..31 garbage)
    const float* __restrict__ featx,         // [NN][8]
    float* __restrict__ bil24,               // [NSLOT][CC][NN] partials
    float* __restrict__ s2T,                 // [CC][NN] spatial out
    const int* __restrict__ tab)             // pairs: [key, slot]
{
    __shared__ float smem[6176];             // bilateral: 3072; blur: 4992+1152+32
    const int tid = threadIdx.x;
    const int item = tab[2*blockIdx.x];
    const int slot = tab[2*blockIdx.x + 1];

    if (item < BLURKEY) {
        // ---------------- bilateral partial: one (n-tile, m-chunk)
        float* lds_h = smem;
        const int wv   = tid >> 6, lane = tid & 63;
        const int quad = lane >> 5, lid = lane & 31;

        const int nt = item >> 5, mc = item & 31;
        const int ny0 = (nt / 6) * 16, nx0 = (nt % 6) * 16;
        const int my0 = (mc & 3) * 24, mx0 = (mc >> 2) * 16;

        const int dx = (mx0 > nx0 + 15) ? mx0 - (nx0 + 15)
                     : ((nx0 > mx0 + 15) ? nx0 - (mx0 + 15) : 0);
        const int lim = TRUNC2 - dx * dx;            // >= 0 (host-culled)
        int T = (int)sqrtf((float)lim);
        T -= (T * T > lim);
        T += ((T + 1) * (T + 1) <= lim);

        int blo = ny0 - T - my0;      blo = blo < 0 ? 0 : blo;
        int bhi = ny0 + 15 + T - my0; bhi = bhi > 23 ? 23 : bhi;

        {   // stage featx rows blo..bhi: [seg][16 px][8 floats]
            float4* dst = (float4*)lds_h;
            for (int i = blo * 32 + tid; i < (bhi + 1) * 32; i += 256) {
                const int seg = i >> 5, off = i & 31;
                dst[i] = ((const float4*)(featx +
                          (size_t)((my0 + seg) * WW + mx0) * 8))[off];
            }
        }
        __syncthreads();

        // per-wave m-row range
        const int by0 = ny0 + 4 * wv;
        int lo = by0 - T - my0;     lo = lo < 0 ? 0 : lo;
        int hi = by0 + 3 + T - my0; hi = hi > 23 ? 23 : hi;

        const int row = lid >> 4, col = lid & 15;
        const int n0 = (by0 + row) * WW + nx0 + col;     // acc0 pixel
        const int n1 = n0 + 2 * WW;                      // acc1 pixel
        const float4 g0a = *(const float4*)(featx + (size_t)n0 * 8);
        const float2 g0b = *(const float2*)(featx + (size_t)n0 * 8 + 4);
        const float4 g1a = *(const float4*)(featx + (size_t)n1 * 8);
        const float2 g1b = *(const float2*)(featx + (size_t)n1 * 8 + 4);

        f32x16 acc0, acc1;
        #pragma unroll
        for (int r = 0; r < 16; r++) { acc0[r] = 0.f; acc1[r] = 0.f; }

        if (lo <= hi) {                                  // wave-uniform
            int mg = (my0 + lo) * WW + mx0 + quad * 8;
            #pragma unroll 1
            for (int step = lo; step <= hi; step++, mg += WW) {
                bf16x8 afrag = *(const bf16x8*)(pT + (size_t)lid * NN + mg);

                const float* h = lds_h + (step * 16 + quad * 8) * 8;
                float kb0[8], kb1[8];
                #pragma unroll
                for (int j = 0; j < 8; j++) {
                    float4 ha = *(const float4*)(h + j * 8);
                    float2 hb = *(const float2*)(h + j * 8 + 4);
                    float s0 = g0a.x + ha.x;
                    s0 = fmaf(g0a.y, ha.y, s0);
                    s0 = fmaf(g0a.z, ha.z, s0);
                    s0 = fmaf(g0a.w, ha.w, s0);
                    s0 = fmaf(g0b.x, hb.x, s0);
                    s0 = fmaf(g0b.y, hb.y, s0);
                    kb0[j] = fexp2(s0);
                    float s1 = g1a.x + ha.x;
                    s1 = fmaf(g1a.y, ha.y, s1);
                    s1 = fmaf(g1a.z, ha.z, s1);
                    s1 = fmaf(g1a.w, ha.w, s1);
                    s1 = fmaf(g1b.x, hb.x, s1);
                    s1 = fmaf(g1b.y, hb.y, s1);
                    kb1[j] = fexp2(s1);
                }
                bf16x8 b0, b1;
                #pragma unroll
                for (int j = 0; j < 8; j++) { b0[j] = f2b(kb0[j]); b1[j] = f2b(kb1[j]); }

                acc0 = __builtin_amdgcn_mfma_f32_32x32x16_bf16(afrag, b0, acc0, 0, 0, 0);
                acc1 = __builtin_amdgcn_mfma_f32_32x32x16_bf16(afrag, b1, acc1, 0, 0, 0);
            }
        }

        // D layout: col(n) = lid, row(c) = (r&3) + 8*(r>>2) + 4*quad
        // Plain stores to the private slot (full overwrite of the slot-tile;
        // waves with empty ranges store zeros — correct, K~0 there).
        float* dst = bil24 + (size_t)slot * CC * NN;
        #pragma unroll
        for (int r = 0; r < 16; r++) {
            int c = (r & 3) + 8 * (r >> 2) + 4 * quad;
            if (c < CC) {
                dst[(size_t)c * NN + n0] = acc0[r];
                dst[(size_t)c * NN + n1] = acc1[r];
            }
        }
    } else {
        // ---------------- spatial blur, one (channel, 12-row strip) per block
        float* A   = smem;           // up to 52 rows x 96
        float* B2  = smem + 4992;    // 12 x 96
        float* w_s = smem + 6144;    // 21 weights
        const int b2 = item - BLURKEY;
        const int c = b2 % CC;
        const int strip = b2 / CC;
        const int y0 = strip * SROWS;
        const int ylo = (y0 - RS < 0) ? 0 : y0 - RS;
        const int yhi = (y0 + SROWS - 1 + RS > HH - 1) ? HH - 1 : y0 + SROWS - 1 + RS;
        const int nrows = yhi - ylo + 1;

        if (tid <= RS) w_s[tid] = fexp2(-(float)(tid*tid) * (L2E / 18.f));
        const __hip_bfloat16* src = pT + (size_t)c * NN + ylo * WW;
        for (int i = tid; i < nrows * WW; i += 256)
            A[i] = __bfloat162float(src[i]);
        __syncthreads();

        for (int i = tid; i < SROWS * WW; i += 256) {
            const int yo = y0 + i / WW;
            const int x  = i % WW;
            float acc = A[(yo - ylo) * WW + x];
            #pragma unroll
            for (int d = 1; d <= RS; d++) {
                float s = 0.f;
                if (yo - d >= 0)  s += A[(yo - d - ylo) * WW + x];
                if (yo + d < HH)  s += A[(yo + d - ylo) * WW + x];
                acc = fmaf(w_s[d], s, acc);
            }
            B2[i] = acc;
        }
        __syncthreads();

        for (int i = tid; i < SROWS * WW; i += 256) {
            const int r = i / WW, x = i % WW;
            float acc = B2[i];
            #pragma unroll
            for (int d = 1; d <= RS; d++) {
                float s = 0.f;
                if (x - d >= 0)  s += B2[r * WW + x - d];
                if (x + d < WW)  s += B2[r * WW + x + d];
                acc = fmaf(w_s[d], s, acc);
            }
            s2T[(size_t)c * NN + (y0 + r) * WW + x] = acc;
        }
    }
}

// Combine slots + spatial, compat, q-update, fused softmax -> pT.
// Grid NN/64 x 128 threads, 2 lanes per pixel (parity-split over cp).
__global__ __launch_bounds__(128) void k_update(
    const float* __restrict__ bil24, const float* __restrict__ s2T,
    const float* __restrict__ uf, const float* __restrict__ par,
    const int* __restrict__ flag32, const int* __restrict__ cnt_tab,
    __hip_bfloat16* __restrict__ pT, void* __restrict__ out, int last)
{
    __shared__ float sc[CC*CC + 1];
    __shared__ float sws[CC], swb[CC];
    const int tid = threadIdx.x;
    for (int i = tid; i < CC*CC; i += 128) sc[i] = par[2*CC + i];
    if (tid == 0) sc[CC*CC] = 0.f;
    if (tid < CC) { sws[tid] = par[tid]; swb[tid] = par[CC + tid]; }
    __syncthreads();

    const int half = tid & 1;
    const int n = blockIdx.x * 64 + (tid >> 1);
    const int nt = ((n / WW) >> 4) * 6 + ((n % WW) >> 4);
    const int cnt = cnt_tab[nt];

    float mb[11];
    #pragma unroll
    for (int k = 0; k < 11; k++) mb[k] = 0.f;
    #pragma unroll 1
    for (int sl = 0; sl < cnt; sl++) {
        const float* base = bil24 + (size_t)sl * CC * NN + n;
        #pragma unroll
        for (int k = 0; k < 11; k++) {
            const int cp = 2*k + half;
            if (cp < CC) mb[k] += base[(size_t)cp * NN];
        }
    }

    float msg[11];
    #pragma unroll
    for (int k = 0; k < 11; k++) {
        const int cp = 2*k + half;
        if (cp < CC)
            msg[k] = fmaf(s2T[(size_t)cp*NN + n], sws[cp], mb[k] * swb[cp]);
        else msg[k] = 0.f;
    }

    float pw[CC];
    #pragma unroll
    for (int c = 0; c < CC; c++) {
        float a = msg[0] * sc[c*CC + half];
        #pragma unroll
        for (int k = 1; k < 11; k++)
            a = fmaf(msg[k], sc[c*CC + 2*k + half], a);   // k=10,half=1 -> pad 0
        pw[c] = a;
    }
    #pragma unroll
    for (int c = 0; c < CC; c++)
        pw[c] += __shfl_xor(pw[c], 1, 64);

    float qv[CC];
    float mx = -1e30f;
    #pragma unroll
    for (int c = 0; c < CC; c++) {
        qv[c] = uf[(size_t)n*CC + c] - pw[c];
        mx = fmaxf(mx, qv[c]);
    }

    if (last) {
        const int is_f32 = rdflag(flag32);
        #pragma unroll
        for (int k = 0; k < 11; k++) {
            const int ce = 2*k, co = (k < 10) ? 2*k + 1 : 0;
            float v = half ? qv[co] : qv[ce];          // static reg indices
            const int c = 2*k + half;
            if (c < CC) {
                if (is_f32) ((float*)out)[(size_t)n*CC + c] = v;
                else ((__hip_bfloat16*)out)[(size_t)n*CC + c] = __float2bfloat16(v);
            }
        }
    } else {
        float ex[11]; float ssum = 0.f;
        #pragma unroll
        for (int k = 0; k < 11; k++) {
            const int ce = 2*k, co = (k < 10) ? 2*k + 1 : 0;
            float v = half ? qv[co] : qv[ce];
            float e = fexp(v - mx);
            if (2*k + half < CC) ssum += e;
            ex[k] = e;
        }
        ssum += __shfl_xor(ssum, 1, 64);
        const float inv = 1.f / ssum;
        #pragma unroll
        for (int k = 0; k < 11; k++) {
            const int c = 2*k + half;
            if (c < CC) pT[(size_t)c*NN + n] = __float2bfloat16(ex[k] * inv);
        }
    }
}

extern "C" void kernel_launch(void* const* d_in, const int* in_sizes, int n_in,
                              void* d_out, int out_size, void* d_ws, size_t ws_size,
                              hipStream_t stream)
{
    // ---- static work table: culled survivors, per-n-tile slot ranks, LPT order
    static std::vector<int> h_tab;          // pairs [key, slot]
    static int h_cnt[36];
    static int h_n = 0;
    if (h_n == 0) {
        struct It { int key, slot, cost; };
        std::vector<It> its;
        for (int nt = 0; nt < 36; nt++) {
            h_cnt[nt] = 0;
            const int ny0 = (nt/6)*16, nx0 = (nt%6)*16;
            for (int mc = 0; mc < 24; mc++) {
                const int my0 = (mc&3)*24, mx0 = (mc>>2)*16;
                const int dx = (mx0 > nx0+15) ? mx0-(nx0+15)
                             : ((nx0 > mx0+15) ? nx0-(mx0+15) : 0);
                const int lim = TRUNC2 - dx*dx;
                if (lim < 0) continue;
                int T = (int)std::sqrt((double)lim);
                while (T*T > lim) T--;
                while ((T+1)*(T+1) <= lim) T++;
                int cost = 0;
                for (int wv = 0; wv < 4; wv++) {
                    const int by0 = ny0 + 4*wv;
                    int lo = by0 - T - my0;     if (lo < 0)  lo = 0;
                    int hi = by0 + 3 + T - my0; if (hi > 23) hi = 23;
                    if (lo <= hi) cost += hi - lo + 1;
                }
                if (cost == 0) continue;
                its.push_back({(nt << 5) | mc, h_cnt[nt]++, cost});
            }
        }
        for (int b = 0; b < NBLUR; b++) its.push_back({BLURKEY + b, 0, 20});
        std::sort(its.begin(), its.end(),
                  [](const It& a, const It& b) { return a.cost > b.cost; });
        h_n = (int)its.size();
        h_tab.resize(2 * h_n + 36);
        for (int i = 0; i < h_n; i++) {
            h_tab[2*i]     = its[i].key;
            h_tab[2*i + 1] = its[i].slot;
        }
        for (int t = 0; t < 36; t++) h_tab[2*h_n + t] = h_cnt[t];
    }

    float* ws = (float*)d_ws;
    int*   flag32 = (int*)ws;                    // [0..32)
    float* par    = ws + 32;                     // 483 used
    float* featx  = ws + 544;                    // NN*8 = 73728 floats
    __hip_bfloat16* pT = (__hip_bfloat16*)(ws + 74272);   // 32*NN bf16 = 147456 floats
    float* uf    = ws + 221728;                  // NELEM
    float* s2T   = uf + NELEM;                   // NELEM
    float* bil24 = s2T + NELEM;                  // NSLOT*NELEM floats (~18.6 MB)
    int*   d_tab = (int*)(bil24 + (size_t)NSLOT*NELEM);
    const int* d_cnt = d_tab + 2*h_n;

    hipMemcpyAsync(d_tab, h_tab.data(), h_tab.size() * sizeof(int),
                   hipMemcpyHostToDevice, stream);

    k_sniff<<<32, 256, 0, stream>>>((const unsigned short*)d_in[0], flag32);
    k_prep<<<NN/256, 256, 0, stream>>>(d_in[0], d_in[1], d_in[2], d_in[3], d_in[4],
                                       flag32, uf, featx, par, pT);

    for (int it = 0; it < 5; it++) {
        k_work<<<h_n, 256, 0, stream>>>(pT, featx, bil24, s2T, d_tab);
        k_update<<<NN/64, 128, 0, stream>>>(bil24, s2T, uf, par, flag32, d_cnt,
                                            pT, d_out, (it == 4) ? 1 : 0);
    }
}

// Round 8
// 246.938 us; speedup vs baseline: 1.4811x; 1.4811x over previous
//
#include <hip/hip_runtime.h>
#include <hip/hip_bf16.h>

#define HH 96
#define WW 96
#define CC 21
#define NN (HH*WW)          // 9216
#define NELEM (NN*CC)       // 193536
#define RS 20
#define NPAR (2*CC + CC*CC)
#define L2E 1.4426950408889634f
#define NBB (36*24)
#define NBLUR (CC*8)        // 168 blur items
#define SROWS 12
#define TRUNC2 1225         // 35^2
#define BLURKEY 0x10000

typedef short bf16x8 __attribute__((ext_vector_type(8)));
typedef float f32x16 __attribute__((ext_vector_type(16)));

__device__ __forceinline__ float fexp2(float x) { return __builtin_amdgcn_exp2f(x); }
__device__ __forceinline__ float fexp(float x)  { return __builtin_amdgcn_exp2f(x * L2E); }

__device__ __forceinline__ unsigned short f2u(float f) {
    __hip_bfloat16 h = __float2bfloat16(f);
    unsigned short s; __builtin_memcpy(&s, &h, 2); return s;
}

// ---- compile-time work table: culled (n-tile, m-chunk) survivors + blur
// items, LPT order via counting sort. No runtime H2D copy.
struct Tab { int n; int k[NBB + NBLUR]; };
constexpr Tab build_tab() {
    Tab t{};
    int key[NBB + NBLUR] = {};
    int cst[NBB + NBLUR] = {};
    int m = 0;
    for (int nt = 0; nt < 36; nt++)
        for (int mc = 0; mc < 24; mc++) {
            const int ny0 = (nt / 6) * 16, nx0 = (nt % 6) * 16;
            const int my0 = (mc & 3) * 24, mx0 = (mc >> 2) * 16;
            const int dx = (mx0 > nx0 + 15) ? mx0 - (nx0 + 15)
                         : ((nx0 > mx0 + 15) ? nx0 - (mx0 + 15) : 0);
            const int lim = TRUNC2 - dx * dx;
            if (lim < 0) continue;
            int T = 0;
            while ((T + 1) * (T + 1) <= lim) T++;
            int cost = 0;
            for (int wv = 0; wv < 4; wv++) {
                const int by0 = ny0 + 4 * wv;
                int lo = by0 - T - my0;     if (lo < 0)  lo = 0;
                int hi = by0 + 3 + T - my0; if (hi > 23) hi = 23;
                if (lo <= hi) cost += hi - lo + 1;
            }
            if (cost == 0) continue;
            key[m] = (nt << 5) | mc; cst[m] = cost; m++;
        }
    for (int b = 0; b < NBLUR; b++) { key[m] = BLURKEY + b; cst[m] = 20; m++; }
    for (int c = 96; c >= 1; c--)                 // stable counting sort, desc
        for (int i = 0; i < m; i++)
            if (cst[i] == c) t.k[t.n++] = key[i];
    return t;
}
constexpr Tab TT = build_tab();
__device__ __constant__ Tab c_TT = TT;

// ---- dtype sniff: bf16 data never contains exp=0xFF bit patterns.
__global__ void k_sniff(const unsigned short* __restrict__ u16, int* __restrict__ flag32) {
    __shared__ int sfound;
    if (threadIdx.x == 0) sfound = 0;
    __syncthreads();
    const int base = blockIdx.x * (NELEM/32);
    int found = 0;
    for (int i = base + threadIdx.x; i < base + NELEM/32; i += 256) {
        unsigned v = u16[i];
        if ((v & 0x7F80u) == 0x7F80u) found = 1;
    }
    if (found) sfound = 1;
    __syncthreads();
    if (threadIdx.x == 0) flag32[blockIdx.x] = sfound;
}

__device__ __forceinline__ int rdflag(const int* __restrict__ flag32) {
    int f = 0;
    #pragma unroll
    for (int i = 0; i < 32; i++) f |= flag32[i];
    return f;
}

// Fused prep: featx, params, softmax(u) -> pT (c-major) + pT2 (m-major),
// zero bil.
__global__ __launch_bounds__(256) void k_prep(
    const void* __restrict__ u, const void* __restrict__ img,
    const void* __restrict__ wS, const void* __restrict__ wB,
    const void* __restrict__ compat, const int* __restrict__ flag32,
    float* __restrict__ uf, float* __restrict__ featx, float* __restrict__ par,
    float* __restrict__ bil, __hip_bfloat16* __restrict__ pT,
    unsigned short* __restrict__ pT2)
{
    const int f = rdflag(flag32);
    const int tid = threadIdx.x;
    const int n = blockIdx.x * 256 + tid;

    if (blockIdx.x == 0) {
        for (int i = tid; i < NPAR; i += 256) {
            const void* src; int j;
            if (i < CC)        { src = wS;     j = i; }
            else if (i < 2*CC) { src = wB;     j = i - CC; }
            else               { src = compat; j = i - 2*CC; }
            par[i] = f ? ((const float*)src)[j]
                       : __bfloat162float(((const __hip_bfloat16*)src)[j]);
        }
    }
    {
        float c0, c1, c2;
        if (f) { const float* p = (const float*)img;
                 c0 = p[3*n]; c1 = p[3*n+1]; c2 = p[3*n+2]; }
        else   { const __hip_bfloat16* p = (const __hip_bfloat16*)img;
                 c0 = __bfloat162float(p[3*n]); c1 = __bfloat162float(p[3*n+1]);
                 c2 = __bfloat162float(p[3*n+2]); }
        float ym = (float)(n / WW), xm = (float)(n % WW);
        const float sc = 0.15014029f;   // sqrt(2*L2E/128)
        const float cf = 9.6089787f;    // sqrt(64*L2E)
        featx[8*n + 0] = -L2E * (fmaf(ym, ym, xm*xm) * 0.0078125f
                                 + 32.f * (c0*c0 + c1*c1 + c2*c2));
        featx[8*n + 1] = sc * ym;
        featx[8*n + 2] = sc * xm;
        featx[8*n + 3] = cf * c0;
        featx[8*n + 4] = cf * c1;
        featx[8*n + 5] = cf * c2;
        featx[8*n + 6] = 0.f;
        featx[8*n + 7] = 0.f;
    }

    float v[CC];
    float mx = -1e30f;
    #pragma unroll
    for (int c = 0; c < CC; c++) {
        float uv = f ? ((const float*)u)[n*CC + c]
                     : __bfloat162float(((const __hip_bfloat16*)u)[n*CC + c]);
        uf[n*CC + c] = uv;
        v[c] = uv;
        mx = fmaxf(mx, uv);
    }
    float s = 0.f;
    #pragma unroll
    for (int c = 0; c < CC; c++) { v[c] = fexp(v[c] - mx); s += v[c]; }
    float inv = 1.f / s;

    unsigned short ub[CC];
    #pragma unroll
    for (int c = 0; c < CC; c++) {
        float pv = v[c] * inv;
        ub[c] = f2u(pv);
        __hip_bfloat16 h; __builtin_memcpy(&h, &ub[c], 2);
        pT[(size_t)c*NN + n] = h;
        bil[(size_t)c*NN + n] = 0.f;
    }
    // pT2[n][0..31] (64B row), dword d = c=2d | c=2d+1 << 16
    unsigned dw[16];
    #pragma unroll
    for (int d = 0; d < 16; d++) {
        unsigned lo = (2*d     < CC) ? (unsigned)ub[2*d]     : 0u;
        unsigned hi = (2*d + 1 < CC) ? (unsigned)ub[2*d + 1] : 0u;
        dw[d] = lo | (hi << 16);
    }
    unsigned* q = (unsigned*)(pT2 + (size_t)n * 32);
    #pragma unroll
    for (int d = 0; d < 4; d++)
        *(uint4*)(q + 4*d) = *(uint4*)&dw[4*d];
}

// Work kernel: R3 structure exactly (one block per (n-tile, m-chunk), LPT
// order, atomics), but the A-fragment comes from m-major pT2: each of the 8
// ushort loads is one contiguous 64B line per 32-lane quad (vs 64 scattered
// lines for the old per-lane bf16x8 gather).
__global__ __launch_bounds__(256) void k_work(
    const __hip_bfloat16* __restrict__ pT,   // [32][NN] c-major (blur)
    const unsigned short* __restrict__ pT2,  // [NN][32] m-major (bilateral A)
    const float* __restrict__ featx,         // [NN][8]
    float* __restrict__ bil,                 // [CC][NN] atomic accum
    float* __restrict__ s2T)                 // [CC][NN] spatial out
{
    __shared__ float smem[6176];
    const int tid = threadIdx.x;
    const int item = c_TT.k[blockIdx.x];

    if (item < BLURKEY) {
        float* lds_h = smem;
        const int wv   = tid >> 6, lane = tid & 63;
        const int quad = lane >> 5, lid = lane & 31;

        const int nt = item >> 5, mc = item & 31;
        const int ny0 = (nt / 6) * 16, nx0 = (nt % 6) * 16;
        const int my0 = (mc & 3) * 24, mx0 = (mc >> 2) * 16;

        const int dx = (mx0 > nx0 + 15) ? mx0 - (nx0 + 15)
                     : ((nx0 > mx0 + 15) ? nx0 - (mx0 + 15) : 0);
        const int lim = TRUNC2 - dx * dx;            // >= 0 (host-culled)
        int T = (int)sqrtf((float)lim);
        T -= (T * T > lim);
        T += ((T + 1) * (T + 1) <= lim);

        int blo = ny0 - T - my0;      blo = blo < 0 ? 0 : blo;
        int bhi = ny0 + 15 + T - my0; bhi = bhi > 23 ? 23 : bhi;

        {   // stage featx rows blo..bhi: [seg][16 px][8 floats]
            float4* dst = (float4*)lds_h;
            for (int i = blo * 32 + tid; i < (bhi + 1) * 32; i += 256) {
                const int seg = i >> 5, off = i & 31;
                dst[i] = ((const float4*)(featx +
                          (size_t)((my0 + seg) * WW + mx0) * 8))[off];
            }
        }
        __syncthreads();

        // per-wave m-row range
        const int by0 = ny0 + 4 * wv;
        int lo = by0 - T - my0;     lo = lo < 0 ? 0 : lo;
        int hi = by0 + 3 + T - my0; hi = hi > 23 ? 23 : hi;
        if (lo > hi) return;   // wave-uniform; no barriers below

        const int row = lid >> 4, col = lid & 15;
        const int n0 = (by0 + row) * WW + nx0 + col;     // acc0 pixel
        const int n1 = n0 + 2 * WW;                      // acc1 pixel
        const float4 g0a = *(const float4*)(featx + (size_t)n0 * 8);
        const float4 g0b = *(const float4*)(featx + (size_t)n0 * 8 + 4);
        const float4 g1a = *(const float4*)(featx + (size_t)n1 * 8);
        const float4 g1b = *(const float4*)(featx + (size_t)n1 * 8 + 4);

        f32x16 acc0, acc1;
        #pragma unroll
        for (int r = 0; r < 16; r++) { acc0[r] = 0.f; acc1[r] = 0.f; }

        const int mg0 = (my0 + lo) * WW + mx0 + quad * 8;   // first A m-index
        const unsigned short* ap = pT2 + (size_t)mg0 * 32 + lid;
        #pragma unroll 1
        for (int step = lo; step <= hi; step++, ap += WW * 32) {
            bf16x8 afrag;
            #pragma unroll
            for (int j = 0; j < 8; j++) afrag[j] = (short)ap[j * 32];

            const float* h = lds_h + (step * 16 + quad * 8) * 8;
            float kb0[8], kb1[8];
            #pragma unroll
            for (int j = 0; j < 8; j++) {
                float4 ha = *(const float4*)(h + j * 8);
                float4 hb = *(const float4*)(h + j * 8 + 4);
                float s0 = g0a.x + ha.x;
                s0 = fmaf(g0a.y, ha.y, s0);
                s0 = fmaf(g0a.z, ha.z, s0);
                s0 = fmaf(g0a.w, ha.w, s0);
                s0 = fmaf(g0b.x, hb.x, s0);
                s0 = fmaf(g0b.y, hb.y, s0);
                kb0[j] = fexp2(s0);
                float s1 = g1a.x + ha.x;
                s1 = fmaf(g1a.y, ha.y, s1);
                s1 = fmaf(g1a.z, ha.z, s1);
                s1 = fmaf(g1a.w, ha.w, s1);
                s1 = fmaf(g1b.x, hb.x, s1);
                s1 = fmaf(g1b.y, hb.y, s1);
                kb1[j] = fexp2(s1);
            }
            bf16x8 b0, b1;
            #pragma unroll
            for (int j = 0; j < 8; j++) {
                b0[j] = (short)f2u(kb0[j]);
                b1[j] = (short)f2u(kb1[j]);
            }

            acc0 = __builtin_amdgcn_mfma_f32_32x32x16_bf16(afrag, b0, acc0, 0, 0, 0);
            acc1 = __builtin_amdgcn_mfma_f32_32x32x16_bf16(afrag, b1, acc1, 0, 0, 0);
        }

        // D layout: col(n) = lid, row(c) = (r&3) + 8*(r>>2) + 4*quad
        #pragma unroll
        for (int r = 0; r < 16; r++) {
            int c = (r & 3) + 8 * (r >> 2) + 4 * quad;
            if (c < CC) {
                atomicAdd(&bil[(size_t)c * NN + n0], acc0[r]);
                atomicAdd(&bil[(size_t)c * NN + n1], acc1[r]);
            }
        }
    } else {
        // ---------------- spatial blur, one (channel, 12-row strip) per block
        float* A   = smem;           // up to 52 rows x 96
        float* B2  = smem + 4992;    // 12 x 96
        float* w_s = smem + 6144;    // 21 weights
        const int b2 = item - BLURKEY;
        const int c = b2 % CC;
        const int strip = b2 / CC;
        const int y0 = strip * SROWS;
        const int ylo = (y0 - RS < 0) ? 0 : y0 - RS;
        const int yhi = (y0 + SROWS - 1 + RS > HH - 1) ? HH - 1 : y0 + SROWS - 1 + RS;
        const int nrows = yhi - ylo + 1;

        if (tid <= RS) w_s[tid] = fexp2(-(float)(tid*tid) * (L2E / 18.f));
        const __hip_bfloat16* src = pT + (size_t)c * NN + ylo * WW;
        for (int i = tid; i < nrows * WW; i += 256)
            A[i] = __bfloat162float(src[i]);
        __syncthreads();

        for (int i = tid; i < SROWS * WW; i += 256) {
            const int yo = y0 + i / WW;
            const int x  = i % WW;
            float acc = A[(yo - ylo) * WW + x];
            #pragma unroll
            for (int d = 1; d <= RS; d++) {
                float s = 0.f;
                if (yo - d >= 0)  s += A[(yo - d - ylo) * WW + x];
                if (yo + d < HH)  s += A[(yo + d - ylo) * WW + x];
                acc = fmaf(w_s[d], s, acc);
            }
            B2[i] = acc;
        }
        __syncthreads();

        for (int i = tid; i < SROWS * WW; i += 256) {
            const int r = i / WW, x = i % WW;
            float acc = B2[i];
            #pragma unroll
            for (int d = 1; d <= RS; d++) {
                float s = 0.f;
                if (x - d >= 0)  s += B2[r * WW + x - d];
                if (x + d < WW)  s += B2[r * WW + x + d];
                acc = fmaf(w_s[d], s, acc);
            }
            s2T[(size_t)c * NN + (y0 + r) * WW + x] = acc;
        }
    }
}

// Combine spatial+bilateral, compatibility, q-update, fused softmax -> pT+pT2.
// Two lanes per pixel (parity-split over cp). Re-zeroes bil.
__global__ __launch_bounds__(256) void k_update(
    float* __restrict__ bil, const float* __restrict__ s2T,
    const float* __restrict__ uf, const float* __restrict__ par,
    const int* __restrict__ flag32,
    __hip_bfloat16* __restrict__ pT, unsigned short* __restrict__ pT2,
    void* __restrict__ out, int last)
{
    __shared__ float sc[CC*CC + 1];
    __shared__ float sws[CC], swb[CC];
    const int tid = threadIdx.x;
    for (int i = tid; i < CC*CC; i += 256) sc[i] = par[2*CC + i];
    if (tid == 0) sc[CC*CC] = 0.f;
    if (tid < CC) { sws[tid] = par[tid]; swb[tid] = par[CC + tid]; }
    __syncthreads();

    const int half = tid & 1;                  // cp parity owned by this lane
    const int n = blockIdx.x * 128 + (tid >> 1);

    float msg[11];
    #pragma unroll
    for (int k = 0; k < 11; k++) {
        const int cp = 2*k + half;
        if (cp < CC) {
            msg[k] = fmaf(s2T[(size_t)cp*NN + n], sws[cp],
                          bil[(size_t)cp*NN + n] * swb[cp]);
            bil[(size_t)cp*NN + n] = 0.f;
        } else msg[k] = 0.f;
    }

    float pw[CC];
    #pragma unroll
    for (int c = 0; c < CC; c++) {
        float a = msg[0] * sc[c*CC + half];
        #pragma unroll
        for (int k = 1; k < 11; k++)
            a = fmaf(msg[k], sc[c*CC + 2*k + half], a);   // k=10,half=1 -> pad 0
        pw[c] = a;
    }
    #pragma unroll
    for (int c = 0; c < CC; c++)
        pw[c] += __shfl_xor(pw[c], 1, 64);

    float qv[CC];
    float mx = -1e30f;
    #pragma unroll
    for (int c = 0; c < CC; c++) {
        qv[c] = uf[(size_t)n*CC + c] - pw[c];
        mx = fmaxf(mx, qv[c]);
    }

    if (last) {
        const int is_f32 = rdflag(flag32);
        #pragma unroll
        for (int k = 0; k < 11; k++) {
            const int ce = 2*k, co = (k < 10) ? 2*k + 1 : 0;
            float v = half ? qv[co] : qv[ce];          // static reg indices
            const int c = 2*k + half;
            if (c < CC) {
                if (is_f32) ((float*)out)[(size_t)n*CC + c] = v;
                else ((__hip_bfloat16*)out)[(size_t)n*CC + c] = __float2bfloat16(v);
            }
        }
    } else {
        float ex[11]; float ssum = 0.f;
        #pragma unroll
        for (int k = 0; k < 11; k++) {
            const int ce = 2*k, co = (k < 10) ? 2*k + 1 : 0;
            float v = half ? qv[co] : qv[ce];
            float e = fexp(v - mx);
            if (2*k + half < CC) ssum += e;
            ex[k] = e;
        }
        ssum += __shfl_xor(ssum, 1, 64);
        const float inv = 1.f / ssum;

        unsigned short b[11];
        #pragma unroll
        for (int k = 0; k < 11; k++) {
            const int c = 2*k + half;
            if (c < CC) {
                float pv = ex[k] * inv;
                b[k] = f2u(pv);
                __hip_bfloat16 h; __builtin_memcpy(&h, &b[k], 2);
                pT[(size_t)c*NN + n] = h;
            } else b[k] = 0;
        }
        // pT2[n][0..31]: dword d = even-lane b[d] | odd-lane b[d] << 16
        unsigned dw[16];
        #pragma unroll
        for (int d = 0; d < 16; d++) {
            unsigned mine  = (d < 11) ? (unsigned)b[d] : 0u;
            unsigned other = (unsigned)__shfl_xor((int)mine, 1, 64) & 0xFFFFu;
            unsigned lo = half ? other : mine;
            unsigned hi = half ? mine  : other;
            dw[d] = lo | (hi << 16);
        }
        unsigned* q = (unsigned*)(pT2 + (size_t)n * 32);
        if (half == 0) {
            *(uint4*)(q + 0) = *(uint4*)&dw[0];
            *(uint4*)(q + 4) = *(uint4*)&dw[4];
        } else {
            *(uint4*)(q + 8)  = *(uint4*)&dw[8];
            *(uint4*)(q + 12) = *(uint4*)&dw[12];
        }
    }
}

extern "C" void kernel_launch(void* const* d_in, const int* in_sizes, int n_in,
                              void* d_out, int out_size, void* d_ws, size_t ws_size,
                              hipStream_t stream)
{
    float* ws = (float*)d_ws;
    int*   flag32 = (int*)ws;                    // [0..32)
    float* par    = ws + 32;                     // 483 used
    float* featx  = ws + 544;                    // NN*8 = 73728 floats
    __hip_bfloat16* pT = (__hip_bfloat16*)(ws + 74272);      // 32*NN bf16 = 147456 floats
    unsigned short* pT2 = (unsigned short*)(ws + 221728);    // NN*32 bf16 = 147456 floats
    float* uf  = ws + 369184;                    // NELEM
    float* s2T = uf + NELEM;                     // NELEM (c-major)
    float* bil = s2T + NELEM;                    // NELEM (c-major); total ~3.8 MB

    k_sniff<<<32, 256, 0, stream>>>((const unsigned short*)d_in[0], flag32);
    k_prep<<<NN/256, 256, 0, stream>>>(d_in[0], d_in[1], d_in[2], d_in[3], d_in[4],
                                       flag32, uf, featx, par, bil, pT, pT2);

    for (int it = 0; it < 5; it++) {
        k_work<<<TT.n, 256, 0, stream>>>(pT, pT2, featx, bil, s2T);
        k_update<<<NN/128, 256, 0, stream>>>(bil, s2T, uf, par, flag32,
                                             pT, pT2, d_out, (it == 4) ? 1 : 0);
    }
}

// Round 9
// 239.930 us; speedup vs baseline: 1.5243x; 1.0292x over previous
//
#include <hip/hip_runtime.h>
#include <hip/hip_bf16.h>

#define HH 96
#define WW 96
#define CC 21
#define NN (HH*WW)          // 9216
#define NELEM (NN*CC)       // 193536
#define RS 20
#define NPAR (2*CC + CC*CC)
#define L2E 1.4426950408889634f
#define NMC 48              // 12x16 m-chunks: 8 y * 6 x
#define NBB (36*NMC)
#define NBLUR (CC*8)        // 168 blur items
#define SROWS 12
#define TRUNC2 1225         // 35^2: dropped mass ~0.028 -> <4e-3 in q, vs 0.099 thr
#define BLURKEY 0x10000

typedef short bf16x8 __attribute__((ext_vector_type(8)));
typedef float f32x16 __attribute__((ext_vector_type(16)));

__device__ __forceinline__ float fexp2(float x) { return __builtin_amdgcn_exp2f(x); }
__device__ __forceinline__ float fexp(float x)  { return __builtin_amdgcn_exp2f(x * L2E); }

__device__ __forceinline__ short f2b(float f) {
    __hip_bfloat16 h = __float2bfloat16(f);
    short s; __builtin_memcpy(&s, &h, 2); return s;
}

// ---- compile-time work table: culled (n-tile, 12x16 m-chunk) survivors +
// blur items, LPT order via stable counting sort. No runtime H2D copy.
struct Tab { int n; int k[NBB + NBLUR]; };
constexpr Tab build_tab() {
    Tab t{};
    int key[NBB + NBLUR] = {};
    int cst[NBB + NBLUR] = {};
    int m = 0;
    for (int nt = 0; nt < 36; nt++)
        for (int mc = 0; mc < NMC; mc++) {
            const int ny0 = (nt / 6) * 16, nx0 = (nt % 6) * 16;
            const int my0 = (mc & 7) * 12, mx0 = (mc >> 3) * 16;
            const int dx = (mx0 > nx0 + 15) ? mx0 - (nx0 + 15)
                         : ((nx0 > mx0 + 15) ? nx0 - (mx0 + 15) : 0);
            const int lim = TRUNC2 - dx * dx;
            if (lim < 0) continue;
            int T = 0;
            while ((T + 1) * (T + 1) <= lim) T++;
            int cost = 0;
            for (int wv = 0; wv < 4; wv++) {
                const int by0 = ny0 + 4 * wv;
                int lo = by0 - T - my0;     if (lo < 0)  lo = 0;
                int hi = by0 + 3 + T - my0; if (hi > 11) hi = 11;
                if (lo <= hi) cost += hi - lo + 1;
            }
            if (cost == 0) continue;
            key[m] = (nt << 6) | mc; cst[m] = cost; m++;
        }
    for (int b = 0; b < NBLUR; b++) { key[m] = BLURKEY + b; cst[m] = 20; m++; }
    for (int c = 48; c >= 1; c--)                 // stable counting sort, desc
        for (int i = 0; i < m; i++)
            if (cst[i] == c) t.k[t.n++] = key[i];
    return t;
}
constexpr Tab TT = build_tab();
__device__ __constant__ Tab c_TT = TT;

// ---- dtype sniff: bf16 data never contains exp=0xFF bit patterns.
__global__ void k_sniff(const unsigned short* __restrict__ u16, int* __restrict__ flag32) {
    __shared__ int sfound;
    if (threadIdx.x == 0) sfound = 0;
    __syncthreads();
    const int base = blockIdx.x * (NELEM/32);
    int found = 0;
    for (int i = base + threadIdx.x; i < base + NELEM/32; i += 256) {
        unsigned v = u16[i];
        if ((v & 0x7F80u) == 0x7F80u) found = 1;
    }
    if (found) sfound = 1;
    __syncthreads();
    if (threadIdx.x == 0) flag32[blockIdx.x] = sfound;
}

__device__ __forceinline__ int rdflag(const int* __restrict__ flag32) {
    int f = 0;
    #pragma unroll
    for (int i = 0; i < 32; i++) f |= flag32[i];   // uniform -> scalar loads
    return f;
}

// Fused prep: convert u -> uf, softmax -> pT (bf16 c-major), build featx,
// convert params, zero bil. Grid 36x256 (one thread per pixel).
__global__ __launch_bounds__(256) void k_prep(
    const void* __restrict__ u, const void* __restrict__ img,
    const void* __restrict__ wS, const void* __restrict__ wB,
    const void* __restrict__ compat, const int* __restrict__ flag32,
    float* __restrict__ uf, float* __restrict__ featx, float* __restrict__ par,
    float* __restrict__ bil, __hip_bfloat16* __restrict__ pT)
{
    const int f = rdflag(flag32);
    const int tid = threadIdx.x;
    const int n = blockIdx.x * 256 + tid;

    if (blockIdx.x == 0) {
        for (int i = tid; i < NPAR; i += 256) {
            const void* src; int j;
            if (i < CC)        { src = wS;     j = i; }
            else if (i < 2*CC) { src = wB;     j = i - CC; }
            else               { src = compat; j = i - 2*CC; }
            par[i] = f ? ((const float*)src)[j]
                       : __bfloat162float(((const __hip_bfloat16*)src)[j]);
        }
    }

    {
        float c0, c1, c2;
        if (f) { const float* p = (const float*)img;
                 c0 = p[3*n]; c1 = p[3*n+1]; c2 = p[3*n+2]; }
        else   { const __hip_bfloat16* p = (const __hip_bfloat16*)img;
                 c0 = __bfloat162float(p[3*n]); c1 = __bfloat162float(p[3*n+1]);
                 c2 = __bfloat162float(p[3*n+2]); }
        float ym = (float)(n / WW), xm = (float)(n % WW);
        const float sc = 0.15014029f;   // sqrt(2*L2E/128)
        const float cf = 9.6089787f;    // sqrt(64*L2E)
        featx[8*n + 0] = -L2E * (fmaf(ym, ym, xm*xm) * 0.0078125f
                                 + 32.f * (c0*c0 + c1*c1 + c2*c2));
        featx[8*n + 1] = sc * ym;
        featx[8*n + 2] = sc * xm;
        featx[8*n + 3] = cf * c0;
        featx[8*n + 4] = cf * c1;
        featx[8*n + 5] = cf * c2;
        featx[8*n + 6] = 0.f;
        featx[8*n + 7] = 0.f;
    }

    float v[CC];
    float mx = -1e30f;
    #pragma unroll
    for (int c = 0; c < CC; c++) {
        float uv = f ? ((const float*)u)[n*CC + c]
                     : __bfloat162float(((const __hip_bfloat16*)u)[n*CC + c]);
        uf[n*CC + c] = uv;
        v[c] = uv;
        mx = fmaxf(mx, uv);
    }
    float s = 0.f;
    #pragma unroll
    for (int c = 0; c < CC; c++) { v[c] = fexp(v[c] - mx); s += v[c]; }
    float inv = 1.f / s;
    #pragma unroll
    for (int c = 0; c < CC; c++) {
        pT[(size_t)c*NN + n] = __float2bfloat16(v[c] * inv);
        bil[(size_t)c*NN + n] = 0.f;
    }
}

// Work kernel: R3 structure, but 12x16 m-chunks -> ~2x non-empty waves
// (~4.8/SIMD vs ~2.5) with half-length serial chains per wave.
__global__ __launch_bounds__(256) void k_work(
    const __hip_bfloat16* __restrict__ pT,   // [32][NN] bf16 (rows 21..31 garbage)
    const float* __restrict__ featx,         // [NN][8]
    float* __restrict__ bil,                 // [CC][NN] atomic accum
    float* __restrict__ s2T)                 // [CC][NN] spatial out
{
    __shared__ float smem[6176];             // bilateral: 1536; blur: 4992+1152+32
    const int tid = threadIdx.x;
    const int item = c_TT.k[blockIdx.x];

    if (item < BLURKEY) {
        // ---------------- bilateral: bil[c][n] += sum_m pT[c][m] * K(n,m)
        float* lds_h = smem;
        const int wv   = tid >> 6, lane = tid & 63;
        const int quad = lane >> 5, lid = lane & 31;

        const int nt = item >> 6, mc = item & 63;
        const int ny0 = (nt / 6) * 16, nx0 = (nt % 6) * 16;
        const int my0 = (mc & 7) * 12, mx0 = (mc >> 3) * 16;

        const int dx = (mx0 > nx0 + 15) ? mx0 - (nx0 + 15)
                     : ((nx0 > mx0 + 15) ? nx0 - (mx0 + 15) : 0);
        const int lim = TRUNC2 - dx * dx;            // >= 0 (host-culled)
        int T = (int)sqrtf((float)lim);
        T -= (T * T > lim);
        T += ((T + 1) * (T + 1) <= lim);

        // block-union m-row range (for staging), within the 12-row chunk
        int blo = ny0 - T - my0;      blo = blo < 0 ? 0 : blo;
        int bhi = ny0 + 15 + T - my0; bhi = bhi > 11 ? 11 : bhi;

        {   // stage featx rows blo..bhi: [seg][16 px][8 floats]
            float4* dst = (float4*)lds_h;
            for (int i = blo * 32 + tid; i < (bhi + 1) * 32; i += 256) {
                const int seg = i >> 5, off = i & 31;
                dst[i] = ((const float4*)(featx +
                          (size_t)((my0 + seg) * WW + mx0) * 8))[off];
            }
        }
        __syncthreads();

        // per-wave m-row range (wave covers n-rows ny0+4wv .. ny0+4wv+3)
        const int by0 = ny0 + 4 * wv;
        int lo = by0 - T - my0;     lo = lo < 0 ? 0 : lo;
        int hi = by0 + 3 + T - my0; hi = hi > 11 ? 11 : hi;
        if (lo > hi) return;   // wave-uniform; no barriers below

        const int row = lid >> 4, col = lid & 15;
        const int n0 = (by0 + row) * WW + nx0 + col;     // acc0 pixel
        const int n1 = n0 + 2 * WW;                      // acc1 pixel
        const float4 g0a = *(const float4*)(featx + (size_t)n0 * 8);
        const float4 g0b = *(const float4*)(featx + (size_t)n0 * 8 + 4);
        const float4 g1a = *(const float4*)(featx + (size_t)n1 * 8);
        const float4 g1b = *(const float4*)(featx + (size_t)n1 * 8 + 4);

        f32x16 acc0, acc1;
        #pragma unroll
        for (int r = 0; r < 16; r++) { acc0[r] = 0.f; acc1[r] = 0.f; }

        int mg = (my0 + lo) * WW + mx0 + quad * 8;   // afrag global base
        #pragma unroll 1
        for (int step = lo; step <= hi; step++, mg += WW) {
            bf16x8 afrag = *(const bf16x8*)(pT + (size_t)lid * NN + mg);

            const float* h = lds_h + (step * 16 + quad * 8) * 8;
            float kb0[8], kb1[8];
            #pragma unroll
            for (int j = 0; j < 8; j++) {
                float4 ha = *(const float4*)(h + j * 8);
                float4 hb = *(const float4*)(h + j * 8 + 4);
                float s0 = g0a.x + ha.x;
                s0 = fmaf(g0a.y, ha.y, s0);
                s0 = fmaf(g0a.z, ha.z, s0);
                s0 = fmaf(g0a.w, ha.w, s0);
                s0 = fmaf(g0b.x, hb.x, s0);
                s0 = fmaf(g0b.y, hb.y, s0);
                kb0[j] = fexp2(s0);
                float s1 = g1a.x + ha.x;
                s1 = fmaf(g1a.y, ha.y, s1);
                s1 = fmaf(g1a.z, ha.z, s1);
                s1 = fmaf(g1a.w, ha.w, s1);
                s1 = fmaf(g1b.x, hb.x, s1);
                s1 = fmaf(g1b.y, hb.y, s1);
                kb1[j] = fexp2(s1);
            }
            bf16x8 b0, b1;
            #pragma unroll
            for (int j = 0; j < 8; j++) { b0[j] = f2b(kb0[j]); b1[j] = f2b(kb1[j]); }

            acc0 = __builtin_amdgcn_mfma_f32_32x32x16_bf16(afrag, b0, acc0, 0, 0, 0);
            acc1 = __builtin_amdgcn_mfma_f32_32x32x16_bf16(afrag, b1, acc1, 0, 0, 0);
        }

        // D layout: col(n) = lid, row(c) = (r&3) + 8*(r>>2) + 4*quad
        #pragma unroll
        for (int r = 0; r < 16; r++) {
            int c = (r & 3) + 8 * (r >> 2) + 4 * quad;
            if (c < CC) {
                atomicAdd(&bil[(size_t)c * NN + n0], acc0[r]);
                atomicAdd(&bil[(size_t)c * NN + n1], acc1[r]);
            }
        }
    } else {
        // ---------------- spatial blur, one (channel, 12-row strip) per block
        float* A   = smem;           // up to 52 rows x 96
        float* B2  = smem + 4992;    // 12 x 96
        float* w_s = smem + 6144;    // 21 weights
        const int b2 = item - BLURKEY;
        const int c = b2 % CC;
        const int strip = b2 / CC;
        const int y0 = strip * SROWS;
        const int ylo = (y0 - RS < 0) ? 0 : y0 - RS;
        const int yhi = (y0 + SROWS - 1 + RS > HH - 1) ? HH - 1 : y0 + SROWS - 1 + RS;
        const int nrows = yhi - ylo + 1;

        if (tid <= RS) w_s[tid] = fexp2(-(float)(tid*tid) * (L2E / 18.f));
        const __hip_bfloat16* src = pT + (size_t)c * NN + ylo * WW;
        for (int i = tid; i < nrows * WW; i += 256)
            A[i] = __bfloat162float(src[i]);
        __syncthreads();

        for (int i = tid; i < SROWS * WW; i += 256) {
            const int yo = y0 + i / WW;
            const int x  = i % WW;
            float acc = A[(yo - ylo) * WW + x];
            #pragma unroll
            for (int d = 1; d <= RS; d++) {
                float s = 0.f;
                if (yo - d >= 0)  s += A[(yo - d - ylo) * WW + x];
                if (yo + d < HH)  s += A[(yo + d - ylo) * WW + x];
                acc = fmaf(w_s[d], s, acc);
            }
            B2[i] = acc;
        }
        __syncthreads();

        for (int i = tid; i < SROWS * WW; i += 256) {
            const int r = i / WW, x = i % WW;
            float acc = B2[i];
            #pragma unroll
            for (int d = 1; d <= RS; d++) {
                float s = 0.f;
                if (x - d >= 0)  s += B2[r * WW + x - d];
                if (x + d < WW)  s += B2[r * WW + x + d];
                acc = fmaf(w_s[d], s, acc);
            }
            s2T[(size_t)c * NN + (y0 + r) * WW + x] = acc;
        }
    }
}

// Combine spatial+bilateral, compatibility, q-update, fused softmax -> pT.
// Two lanes per pixel (parity-split over cp). Re-zeroes bil.
__global__ __launch_bounds__(256) void k_update(
    float* __restrict__ bil, const float* __restrict__ s2T,
    const float* __restrict__ uf, const float* __restrict__ par,
    const int* __restrict__ flag32,
    __hip_bfloat16* __restrict__ pT, void* __restrict__ out, int last)
{
    __shared__ float sc[CC*CC + 1];
    __shared__ float sws[CC], swb[CC];
    const int tid = threadIdx.x;
    for (int i = tid; i < CC*CC; i += 256) sc[i] = par[2*CC + i];
    if (tid == 0) sc[CC*CC] = 0.f;             // pad for parity-indexed reads
    if (tid < CC) { sws[tid] = par[tid]; swb[tid] = par[CC + tid]; }
    __syncthreads();

    const int half = tid & 1;                  // cp parity owned by this lane
    const int n = blockIdx.x * 128 + (tid >> 1);

    float msg[11];
    #pragma unroll
    for (int k = 0; k < 11; k++) {
        const int cp = 2*k + half;
        if (cp < CC) {
            msg[k] = fmaf(s2T[(size_t)cp*NN + n], sws[cp],
                          bil[(size_t)cp*NN + n] * swb[cp]);
            bil[(size_t)cp*NN + n] = 0.f;
        } else msg[k] = 0.f;
    }

    float pw[CC];
    #pragma unroll
    for (int c = 0; c < CC; c++) {
        float a = msg[0] * sc[c*CC + half];
        #pragma unroll
        for (int k = 1; k < 11; k++)
            a = fmaf(msg[k], sc[c*CC + 2*k + half], a);   // k=10,half=1 -> pad 0
        pw[c] = a;
    }
    #pragma unroll
    for (int c = 0; c < CC; c++)
        pw[c] += __shfl_xor(pw[c], 1, 64);

    float qv[CC];
    float mx = -1e30f;
    #pragma unroll
    for (int c = 0; c < CC; c++) {
        qv[c] = uf[(size_t)n*CC + c] - pw[c];
        mx = fmaxf(mx, qv[c]);
    }

    if (last) {
        const int is_f32 = rdflag(flag32);
        #pragma unroll
        for (int k = 0; k < 11; k++) {
            const int ce = 2*k, co = (k < 10) ? 2*k + 1 : 0;
            float v = half ? qv[co] : qv[ce];          // static reg indices
            const int c = 2*k + half;
            if (c < CC) {
                if (is_f32) ((float*)out)[(size_t)n*CC + c] = v;
                else ((__hip_bfloat16*)out)[(size_t)n*CC + c] = __float2bfloat16(v);
            }
        }
    } else {
        float ex[11]; float ssum = 0.f;
        #pragma unroll
        for (int k = 0; k < 11; k++) {
            const int ce = 2*k, co = (k < 10) ? 2*k + 1 : 0;
            float v = half ? qv[co] : qv[ce];
            float e = fexp(v - mx);
            if (2*k + half < CC) ssum += e;
            ex[k] = e;
        }
        ssum += __shfl_xor(ssum, 1, 64);
        const float inv = 1.f / ssum;
        #pragma unroll
        for (int k = 0; k < 11; k++) {
            const int c = 2*k + half;
            if (c < CC) pT[(size_t)c*NN + n] = __float2bfloat16(ex[k] * inv);
        }
    }
}

extern "C" void kernel_launch(void* const* d_in, const int* in_sizes, int n_in,
                              void* d_out, int out_size, void* d_ws, size_t ws_size,
                              hipStream_t stream)
{
    float* ws = (float*)d_ws;
    int*   flag32 = (int*)ws;                    // [0..32)
    float* par    = ws + 32;                     // 483 used
    float* featx  = ws + 544;                    // NN*8 = 73728 floats
    __hip_bfloat16* pT = (__hip_bfloat16*)(ws + 74272);   // 32*NN bf16 = 147456 floats
    float* uf  = ws + 221728;                    // NELEM
    float* s2T = uf + NELEM;                     // NELEM (c-major)
    float* bil = s2T + NELEM;                    // NELEM (c-major); total ~3.2 MB

    k_sniff<<<32, 256, 0, stream>>>((const unsigned short*)d_in[0], flag32);
    k_prep<<<NN/256, 256, 0, stream>>>(d_in[0], d_in[1], d_in[2], d_in[3], d_in[4],
                                       flag32, uf, featx, par, bil, pT);

    for (int it = 0; it < 5; it++) {
        k_work<<<TT.n, 256, 0, stream>>>(pT, featx, bil, s2T);
        k_update<<<NN/128, 256, 0, stream>>>(bil, s2T, uf, par, flag32,
                                             pT, d_out, (it == 4) ? 1 : 0);
    }
}

// Round 10
// 231.091 us; speedup vs baseline: 1.5826x; 1.0383x over previous
//
#include <hip/hip_runtime.h>
#include <hip/hip_bf16.h>

#define HH 96
#define WW 96
#define CC 21
#define NN (HH*WW)          // 9216
#define NELEM (NN*CC)       // 193536
#define RS 20
#define NPAR (2*CC + CC*CC)
#define L2E 1.4426950408889634f
#define NMC 48              // 12x16 m-chunks: 8 y * 6 x
#define NBB (36*NMC)
#define NBLUR (CC*8)        // 168 blur items
#define SROWS 12
#define TRUNC2 900          // 30^2: dropped rim mass ~0.35*unit -> ~2e-3 in q vs 0.099 thr
#define BLURKEY 0x10000

typedef short bf16x8 __attribute__((ext_vector_type(8)));
typedef float f32x16 __attribute__((ext_vector_type(16)));

__device__ __forceinline__ float fexp2(float x) { return __builtin_amdgcn_exp2f(x); }
__device__ __forceinline__ float fexp(float x)  { return __builtin_amdgcn_exp2f(x * L2E); }

__device__ __forceinline__ short f2b(float f) {
    __hip_bfloat16 h = __float2bfloat16(f);
    short s; __builtin_memcpy(&s, &h, 2); return s;
}

// ---- compile-time work table: culled (n-tile, 12x16 m-chunk) survivors +
// blur items, LPT order via stable counting sort. No runtime H2D copy.
struct Tab { int n; int k[NBB + NBLUR]; };
constexpr Tab build_tab() {
    Tab t{};
    int key[NBB + NBLUR] = {};
    int cst[NBB + NBLUR] = {};
    int m = 0;
    for (int nt = 0; nt < 36; nt++)
        for (int mc = 0; mc < NMC; mc++) {
            const int ny0 = (nt / 6) * 16, nx0 = (nt % 6) * 16;
            const int my0 = (mc & 7) * 12, mx0 = (mc >> 3) * 16;
            const int dx = (mx0 > nx0 + 15) ? mx0 - (nx0 + 15)
                         : ((nx0 > mx0 + 15) ? nx0 - (mx0 + 15) : 0);
            const int lim = TRUNC2 - dx * dx;
            if (lim < 0) continue;
            int T = 0;
            while ((T + 1) * (T + 1) <= lim) T++;
            int cost = 0;
            for (int wv = 0; wv < 4; wv++) {
                const int by0 = ny0 + 4 * wv;
                int lo = by0 - T - my0;     if (lo < 0)  lo = 0;
                int hi = by0 + 3 + T - my0; if (hi > 11) hi = 11;
                if (lo <= hi) cost += hi - lo + 1;
            }
            if (cost == 0) continue;
            key[m] = (nt << 6) | mc; cst[m] = cost; m++;
        }
    for (int b = 0; b < NBLUR; b++) { key[m] = BLURKEY + b; cst[m] = 20; m++; }
    for (int c = 48; c >= 1; c--)                 // stable counting sort, desc
        for (int i = 0; i < m; i++)
            if (cst[i] == c) t.k[t.n++] = key[i];
    return t;
}
constexpr Tab TT = build_tab();
__device__ __constant__ Tab c_TT = TT;

// ---- dtype sniff: bf16 data never contains exp=0xFF bit patterns.
__global__ void k_sniff(const unsigned short* __restrict__ u16, int* __restrict__ flag32) {
    __shared__ int sfound;
    if (threadIdx.x == 0) sfound = 0;
    __syncthreads();
    const int base = blockIdx.x * (NELEM/32);
    int found = 0;
    for (int i = base + threadIdx.x; i < base + NELEM/32; i += 256) {
        unsigned v = u16[i];
        if ((v & 0x7F80u) == 0x7F80u) found = 1;
    }
    if (found) sfound = 1;
    __syncthreads();
    if (threadIdx.x == 0) flag32[blockIdx.x] = sfound;
}

__device__ __forceinline__ int rdflag(const int* __restrict__ flag32) {
    int f = 0;
    #pragma unroll
    for (int i = 0; i < 32; i++) f |= flag32[i];   // uniform -> scalar loads
    return f;
}

// Fused prep: convert u -> uf, softmax -> pT (bf16 c-major), build featx,
// convert params, zero bil. Grid 36x256 (one thread per pixel).
__global__ __launch_bounds__(256) void k_prep(
    const void* __restrict__ u, const void* __restrict__ img,
    const void* __restrict__ wS, const void* __restrict__ wB,
    const void* __restrict__ compat, const int* __restrict__ flag32,
    float* __restrict__ uf, float* __restrict__ featx, float* __restrict__ par,
    float* __restrict__ bil, __hip_bfloat16* __restrict__ pT)
{
    const int f = rdflag(flag32);
    const int tid = threadIdx.x;
    const int n = blockIdx.x * 256 + tid;

    if (blockIdx.x == 0) {
        for (int i = tid; i < NPAR; i += 256) {
            const void* src; int j;
            if (i < CC)        { src = wS;     j = i; }
            else if (i < 2*CC) { src = wB;     j = i - CC; }
            else               { src = compat; j = i - 2*CC; }
            par[i] = f ? ((const float*)src)[j]
                       : __bfloat162float(((const __hip_bfloat16*)src)[j]);
        }
    }

    {
        float c0, c1, c2;
        if (f) { const float* p = (const float*)img;
                 c0 = p[3*n]; c1 = p[3*n+1]; c2 = p[3*n+2]; }
        else   { const __hip_bfloat16* p = (const __hip_bfloat16*)img;
                 c0 = __bfloat162float(p[3*n]); c1 = __bfloat162float(p[3*n+1]);
                 c2 = __bfloat162float(p[3*n+2]); }
        float ym = (float)(n / WW), xm = (float)(n % WW);
        const float sc = 0.15014029f;   // sqrt(2*L2E/128)
        const float cf = 9.6089787f;    // sqrt(64*L2E)
        featx[8*n + 0] = -L2E * (fmaf(ym, ym, xm*xm) * 0.0078125f
                                 + 32.f * (c0*c0 + c1*c1 + c2*c2));
        featx[8*n + 1] = sc * ym;
        featx[8*n + 2] = sc * xm;
        featx[8*n + 3] = cf * c0;
        featx[8*n + 4] = cf * c1;
        featx[8*n + 5] = cf * c2;
        featx[8*n + 6] = 0.f;
        featx[8*n + 7] = 0.f;
    }

    float v[CC];
    float mx = -1e30f;
    #pragma unroll
    for (int c = 0; c < CC; c++) {
        float uv = f ? ((const float*)u)[n*CC + c]
                     : __bfloat162float(((const __hip_bfloat16*)u)[n*CC + c]);
        uf[n*CC + c] = uv;
        v[c] = uv;
        mx = fmaxf(mx, uv);
    }
    float s = 0.f;
    #pragma unroll
    for (int c = 0; c < CC; c++) { v[c] = fexp(v[c] - mx); s += v[c]; }
    float inv = 1.f / s;
    #pragma unroll
    for (int c = 0; c < CC; c++) {
        pT[(size_t)c*NN + n] = __float2bfloat16(v[c] * inv);
        bil[(size_t)c*NN + n] = 0.f;
    }
}

// Work kernel: 12x16 m-chunks. __launch_bounds__(256,4) caps VGPR at 128 so
// 4 blocks/CU can be resident; no unroll pragma so the compiler may pipeline
// adjacent (independent) k-steps.
__global__ __launch_bounds__(256, 4) void k_work(
    const __hip_bfloat16* __restrict__ pT,   // [32][NN] bf16 (rows 21..31 garbage)
    const float* __restrict__ featx,         // [NN][8]
    float* __restrict__ bil,                 // [CC][NN] atomic accum
    float* __restrict__ s2T)                 // [CC][NN] spatial out
{
    __shared__ float smem[6176];             // bilateral: 1536; blur: 4992+1152+32
    const int tid = threadIdx.x;
    const int item = c_TT.k[blockIdx.x];

    if (item < BLURKEY) {
        // ---------------- bilateral: bil[c][n] += sum_m pT[c][m] * K(n,m)
        float* lds_h = smem;
        const int wv   = tid >> 6, lane = tid & 63;
        const int quad = lane >> 5, lid = lane & 31;

        const int nt = item >> 6, mc = item & 63;
        const int ny0 = (nt / 6) * 16, nx0 = (nt % 6) * 16;
        const int my0 = (mc & 7) * 12, mx0 = (mc >> 3) * 16;

        const int dx = (mx0 > nx0 + 15) ? mx0 - (nx0 + 15)
                     : ((nx0 > mx0 + 15) ? nx0 - (mx0 + 15) : 0);
        const int lim = TRUNC2 - dx * dx;            // >= 0 (host-culled)
        int T = (int)sqrtf((float)lim);
        T -= (T * T > lim);
        T += ((T + 1) * (T + 1) <= lim);

        // block-union m-row range (for staging), within the 12-row chunk
        int blo = ny0 - T - my0;      blo = blo < 0 ? 0 : blo;
        int bhi = ny0 + 15 + T - my0; bhi = bhi > 11 ? 11 : bhi;

        {   // stage featx rows blo..bhi: [seg][16 px][8 floats]
            float4* dst = (float4*)lds_h;
            for (int i = blo * 32 + tid; i < (bhi + 1) * 32; i += 256) {
                const int seg = i >> 5, off = i & 31;
                dst[i] = ((const float4*)(featx +
                          (size_t)((my0 + seg) * WW + mx0) * 8))[off];
            }
        }
        __syncthreads();

        // per-wave m-row range (wave covers n-rows ny0+4wv .. ny0+4wv+3)
        const int by0 = ny0 + 4 * wv;
        int lo = by0 - T - my0;     lo = lo < 0 ? 0 : lo;
        int hi = by0 + 3 + T - my0; hi = hi > 11 ? 11 : hi;
        if (lo > hi) return;   // wave-uniform; no barriers below

        const int row = lid >> 4, col = lid & 15;
        const int n0 = (by0 + row) * WW + nx0 + col;     // acc0 pixel
        const int n1 = n0 + 2 * WW;                      // acc1 pixel
        const float4 g0a = *(const float4*)(featx + (size_t)n0 * 8);
        const float4 g0b = *(const float4*)(featx + (size_t)n0 * 8 + 4);
        const float4 g1a = *(const float4*)(featx + (size_t)n1 * 8);
        const float4 g1b = *(const float4*)(featx + (size_t)n1 * 8 + 4);

        f32x16 acc0, acc1;
        #pragma unroll
        for (int r = 0; r < 16; r++) { acc0[r] = 0.f; acc1[r] = 0.f; }

        int mg = (my0 + lo) * WW + mx0 + quad * 8;   // afrag global base
        for (int step = lo; step <= hi; step++, mg += WW) {
            bf16x8 afrag = *(const bf16x8*)(pT + (size_t)lid * NN + mg);

            const float* h = lds_h + (step * 16 + quad * 8) * 8;
            float kb0[8], kb1[8];
            #pragma unroll
            for (int j = 0; j < 8; j++) {
                float4 ha = *(const float4*)(h + j * 8);
                float4 hb = *(const float4*)(h + j * 8 + 4);
                float s0 = g0a.x + ha.x;
                s0 = fmaf(g0a.y, ha.y, s0);
                s0 = fmaf(g0a.z, ha.z, s0);
                s0 = fmaf(g0a.w, ha.w, s0);
                s0 = fmaf(g0b.x, hb.x, s0);
                s0 = fmaf(g0b.y, hb.y, s0);
                kb0[j] = fexp2(s0);
                float s1 = g1a.x + ha.x;
                s1 = fmaf(g1a.y, ha.y, s1);
                s1 = fmaf(g1a.z, ha.z, s1);
                s1 = fmaf(g1a.w, ha.w, s1);
                s1 = fmaf(g1b.x, hb.x, s1);
                s1 = fmaf(g1b.y, hb.y, s1);
                kb1[j] = fexp2(s1);
            }
            bf16x8 b0, b1;
            #pragma unroll
            for (int j = 0; j < 8; j++) { b0[j] = f2b(kb0[j]); b1[j] = f2b(kb1[j]); }

            acc0 = __builtin_amdgcn_mfma_f32_32x32x16_bf16(afrag, b0, acc0, 0, 0, 0);
            acc1 = __builtin_amdgcn_mfma_f32_32x32x16_bf16(afrag, b1, acc1, 0, 0, 0);
        }

        // D layout: col(n) = lid, row(c) = (r&3) + 8*(r>>2) + 4*quad
        #pragma unroll
        for (int r = 0; r < 16; r++) {
            int c = (r & 3) + 8 * (r >> 2) + 4 * quad;
            if (c < CC) {
                atomicAdd(&bil[(size_t)c * NN + n0], acc0[r]);
                atomicAdd(&bil[(size_t)c * NN + n1], acc1[r]);
            }
        }
    } else {
        // ---------------- spatial blur, one (channel, 12-row strip) per block
        float* A   = smem;           // up to 52 rows x 96
        float* B2  = smem + 4992;    // 12 x 96
        float* w_s = smem + 6144;    // 21 weights
        const int b2 = item - BLURKEY;
        const int c = b2 % CC;
        const int strip = b2 / CC;
        const int y0 = strip * SROWS;
        const int ylo = (y0 - RS < 0) ? 0 : y0 - RS;
        const int yhi = (y0 + SROWS - 1 + RS > HH - 1) ? HH - 1 : y0 + SROWS - 1 + RS;
        const int nrows = yhi - ylo + 1;

        if (tid <= RS) w_s[tid] = fexp2(-(float)(tid*tid) * (L2E / 18.f));
        const __hip_bfloat16* src = pT + (size_t)c * NN + ylo * WW;
        for (int i = tid; i < nrows * WW; i += 256)
            A[i] = __bfloat162float(src[i]);
        __syncthreads();

        for (int i = tid; i < SROWS * WW; i += 256) {
            const int yo = y0 + i / WW;
            const int x  = i % WW;
            float acc = A[(yo - ylo) * WW + x];
            #pragma unroll
            for (int d = 1; d <= RS; d++) {
                float s = 0.f;
                if (yo - d >= 0)  s += A[(yo - d - ylo) * WW + x];
                if (yo + d < HH)  s += A[(yo + d - ylo) * WW + x];
                acc = fmaf(w_s[d], s, acc);
            }
            B2[i] = acc;
        }
        __syncthreads();

        for (int i = tid; i < SROWS * WW; i += 256) {
            const int r = i / WW, x = i % WW;
            float acc = B2[i];
            #pragma unroll
            for (int d = 1; d <= RS; d++) {
                float s = 0.f;
                if (x - d >= 0)  s += B2[r * WW + x - d];
                if (x + d < WW)  s += B2[r * WW + x + d];
                acc = fmaf(w_s[d], s, acc);
            }
            s2T[(size_t)c * NN + (y0 + r) * WW + x] = acc;
        }
    }
}

// Combine spatial+bilateral, compatibility, q-update, fused softmax -> pT.
// Two lanes per pixel (parity-split over cp). Re-zeroes bil.
__global__ __launch_bounds__(256) void k_update(
    float* __restrict__ bil, const float* __restrict__ s2T,
    const float* __restrict__ uf, const float* __restrict__ par,
    const int* __restrict__ flag32,
    __hip_bfloat16* __restrict__ pT, void* __restrict__ out, int last)
{
    __shared__ float sc[CC*CC + 1];
    __shared__ float sws[CC], swb[CC];
    const int tid = threadIdx.x;
    for (int i = tid; i < CC*CC; i += 256) sc[i] = par[2*CC + i];
    if (tid == 0) sc[CC*CC] = 0.f;             // pad for parity-indexed reads
    if (tid < CC) { sws[tid] = par[tid]; swb[tid] = par[CC + tid]; }
    __syncthreads();

    const int half = tid & 1;                  // cp parity owned by this lane
    const int n = blockIdx.x * 128 + (tid >> 1);

    float msg[11];
    #pragma unroll
    for (int k = 0; k < 11; k++) {
        const int cp = 2*k + half;
        if (cp < CC) {
            msg[k] = fmaf(s2T[(size_t)cp*NN + n], sws[cp],
                          bil[(size_t)cp*NN + n] * swb[cp]);
            bil[(size_t)cp*NN + n] = 0.f;
        } else msg[k] = 0.f;
    }

    float pw[CC];
    #pragma unroll
    for (int c = 0; c < CC; c++) {
        float a = msg[0] * sc[c*CC + half];
        #pragma unroll
        for (int k = 1; k < 11; k++)
            a = fmaf(msg[k], sc[c*CC + 2*k + half], a);   // k=10,half=1 -> pad 0
        pw[c] = a;
    }
    #pragma unroll
    for (int c = 0; c < CC; c++)
        pw[c] += __shfl_xor(pw[c], 1, 64);

    float qv[CC];
    float mx = -1e30f;
    #pragma unroll
    for (int c = 0; c < CC; c++) {
        qv[c] = uf[(size_t)n*CC + c] - pw[c];
        mx = fmaxf(mx, qv[c]);
    }

    if (last) {
        const int is_f32 = rdflag(flag32);
        #pragma unroll
        for (int k = 0; k < 11; k++) {
            const int ce = 2*k, co = (k < 10) ? 2*k + 1 : 0;
            float v = half ? qv[co] : qv[ce];          // static reg indices
            const int c = 2*k + half;
            if (c < CC) {
                if (is_f32) ((float*)out)[(size_t)n*CC + c] = v;
                else ((__hip_bfloat16*)out)[(size_t)n*CC + c] = __float2bfloat16(v);
            }
        }
    } else {
        float ex[11]; float ssum = 0.f;
        #pragma unroll
        for (int k = 0; k < 11; k++) {
            const int ce = 2*k, co = (k < 10) ? 2*k + 1 : 0;
            float v = half ? qv[co] : qv[ce];
            float e = fexp(v - mx);
            if (2*k + half < CC) ssum += e;
            ex[k] = e;
        }
        ssum += __shfl_xor(ssum, 1, 64);
        const float inv = 1.f / ssum;
        #pragma unroll
        for (int k = 0; k < 11; k++) {
            const int c = 2*k + half;
            if (c < CC) pT[(size_t)c*NN + n] = __float2bfloat16(ex[k] * inv);
        }
    }
}

extern "C" void kernel_launch(void* const* d_in, const int* in_sizes, int n_in,
                              void* d_out, int out_size, void* d_ws, size_t ws_size,
                              hipStream_t stream)
{
    float* ws = (float*)d_ws;
    int*   flag32 = (int*)ws;                    // [0..32)
    float* par    = ws + 32;                     // 483 used
    float* featx  = ws + 544;                    // NN*8 = 73728 floats
    __hip_bfloat16* pT = (__hip_bfloat16*)(ws + 74272);   // 32*NN bf16 = 147456 floats
    float* uf  = ws + 221728;                    // NELEM
    float* s2T = uf + NELEM;                     // NELEM (c-major)
    float* bil = s2T + NELEM;                    // NELEM (c-major); total ~3.2 MB

    k_sniff<<<32, 256, 0, stream>>>((const unsigned short*)d_in[0], flag32);
    k_prep<<<NN/256, 256, 0, stream>>>(d_in[0], d_in[1], d_in[2], d_in[3], d_in[4],
                                       flag32, uf, featx, par, bil, pT);

    for (int it = 0; it < 5; it++) {
        k_work<<<TT.n, 256, 0, stream>>>(pT, featx, bil, s2T);
        k_update<<<NN/128, 256, 0, stream>>>(bil, s2T, uf, par, flag32,
                                             pT, d_out, (it == 4) ? 1 : 0);
    }
}